// Round 5
// baseline (491.297 us; speedup 1.0000x reference)
//
#include <hip/hip_runtime.h>
#include <hip/hip_cooperative_groups.h>
#include <math.h>

namespace cg = cooperative_groups;

#define N_PTS     131072
#define G_NUMS    30
#define G_SIZE    100
#define PT_STRIDE (N_PTS / G_NUMS)   // 4369
#define TPB       512
#define NWAVES    (TPB / 64)
#define NBLK      256                // 1 block/CU, cooperative co-residency
#define BINS      4096
#define SHIFT     20
#define SAMPLE_GRPS 1024             // first 4096 points as iid sample
#define RANK_CUT  24                 // 24th-smallest sample -> tau (P(miss) ~ 1e-17)
#define CAP       2048               // global survivor cap per (b,g); E~768
#define CAPB      64                 // per-block per-g LDS buffer; E~24 (Poisson)
#define TIE_CAP   64

__device__ __forceinline__ float dist2f(float px, float py, float pz,
                                        float qx, float qy, float qz) {
    float dx = px - qx, dy = py - qy, dz = pz - qz;
    return fmaf(dx, dx, fmaf(dy, dy, dz * dz));
}

// Smallest bin T with cumulative count >= rank. s_hist populated+synced on entry.
__device__ __forceinline__ unsigned find_bin(unsigned* s_hist, unsigned* s_wsum,
                                             unsigned* s_T, unsigned rank,
                                             int tid, int lane, int wid) {
    unsigned hv[8], csum = 0;
#pragma unroll
    for (int j = 0; j < 8; j++) { hv[j] = s_hist[tid * 8 + j]; csum += hv[j]; }
    unsigned inc = csum;
#pragma unroll
    for (int off = 1; off < 64; off <<= 1) {
        unsigned n = __shfl_up(inc, off);
        if (lane >= off) inc += n;
    }
    __syncthreads();
    if (lane == 63) s_wsum[wid] = inc;
    __syncthreads();
    unsigned base = 0;
    for (int w = 0; w < wid; w++) base += s_wsum[w];
    unsigned c = base + inc - csum;
#pragma unroll
    for (int j = 0; j < 8; j++) {
        if (c < rank && c + hv[j] >= rank) *s_T = (unsigned)(tid * 8 + j);
        c += hv[j];
    }
    __syncthreads();
    return *s_T;
}

// Sampled coarse threshold: distances of first 4096 points -> 4096-bin hist ->
// bin of RANK_CUT-th smallest; tau = bin upper edge.
__device__ unsigned sample_tau(const float4* __restrict__ P4,
                               float qx, float qy, float qz,
                               unsigned* s_hist, unsigned* s_wsum, unsigned* s_T,
                               int tid, int lane, int wid) {
    for (int j = tid; j < BINS; j += TPB) s_hist[j] = 0u;
    if (tid == 0) *s_T = 0u;
    __syncthreads();
    for (int grp = tid; grp < SAMPLE_GRPS; grp += TPB) {
        float4 f0 = P4[3 * grp + 0];
        float4 f1 = P4[3 * grp + 1];
        float4 f2 = P4[3 * grp + 2];
        atomicAdd(&s_hist[__float_as_uint(dist2f(f0.x, f0.y, f0.z, qx, qy, qz)) >> SHIFT], 1u);
        atomicAdd(&s_hist[__float_as_uint(dist2f(f0.w, f1.x, f1.y, qx, qy, qz)) >> SHIFT], 1u);
        atomicAdd(&s_hist[__float_as_uint(dist2f(f1.z, f1.w, f2.x, qx, qy, qz)) >> SHIFT], 1u);
        atomicAdd(&s_hist[__float_as_uint(dist2f(f2.y, f2.z, f2.w, qx, qy, qz)) >> SHIFT], 1u);
    }
    __syncthreads();
    unsigned Tc = find_bin(s_hist, s_wsum, s_T, RANK_CUT, tid, lane, wid);
    return (Tc >= BINS - 1) ? 0xFFFFFFFFu : ((Tc + 1) << SHIFT);
}

// Filter pass: each thread holds 4 points in registers (launch_bounds(512,2)
// gives the 256-VGPR budget so the backend keeps them resident), loops over
// the 30 queries of its batch. Survivors -> per-g LDS buffers -> one flush.
__device__ void filter_phase(const float* __restrict__ pts,
                             const float4* __restrict__ qtau,
                             int* __restrict__ counts, uint2* __restrict__ surv,
                             int B, float4* s_qt, int* s_cnt,
                             uint2 (*s_buf)[CAPB],
                             int tid, int lane, int wid, int blk, int nblk) {
    const int b = blk % B;                  // batch pinned to XCD (blk%8)
    const int nchunks = nblk / B;           // 32
    const int chunk = blk / B;
    const int ppc = N_PTS / nchunks;        // 4096 points per block
    const float4* __restrict__ P4 = (const float4*)(pts + (size_t)b * (N_PTS * 3));

    if (tid < G_NUMS) { s_qt[tid] = qtau[b * G_NUMS + tid]; s_cnt[tid] = 0; }
    __syncthreads();

    const int iters = ppc / (TPB * 4);      // 2
    for (int it = 0; it < iters; ++it) {
        int tri = chunk * (ppc * 3 / 4) + it * (TPB * 3) + tid * 3;
        float4 f0 = P4[tri + 0];
        float4 f1 = P4[tri + 1];
        float4 f2 = P4[tri + 2];
        const int i0 = chunk * ppc + it * (TPB * 4) + tid * 4;
        const float x0 = f0.x, y0 = f0.y, z0 = f0.z;
        const float x1 = f0.w, y1 = f1.x, z1 = f1.y;
        const float x2 = f1.z, y2 = f1.w, z2 = f2.x;
        const float x3 = f2.y, y3 = f2.z, z3 = f2.w;

        for (int g = 0; g < G_NUMS; ++g) {
            float4 qt = s_qt[g];
            const unsigned tau = __float_as_uint(qt.w);
            unsigned u0 = __float_as_uint(dist2f(x0, y0, z0, qt.x, qt.y, qt.z));
            unsigned u1 = __float_as_uint(dist2f(x1, y1, z1, qt.x, qt.y, qt.z));
            unsigned u2 = __float_as_uint(dist2f(x2, y2, z2, qt.x, qt.y, qt.z));
            unsigned u3 = __float_as_uint(dist2f(x3, y3, z3, qt.x, qt.y, qt.z));
            if (u0 < tau) {
                int p = atomicAdd(&s_cnt[g], 1);
                if (p < CAPB) s_buf[g][p] = make_uint2(u0, (unsigned)(i0 + 0));
                else { int gp = atomicAdd(&counts[b * G_NUMS + g], 1);
                       if (gp < CAP) surv[(size_t)(b * G_NUMS + g) * CAP + gp] = make_uint2(u0, (unsigned)(i0 + 0)); }
            }
            if (u1 < tau) {
                int p = atomicAdd(&s_cnt[g], 1);
                if (p < CAPB) s_buf[g][p] = make_uint2(u1, (unsigned)(i0 + 1));
                else { int gp = atomicAdd(&counts[b * G_NUMS + g], 1);
                       if (gp < CAP) surv[(size_t)(b * G_NUMS + g) * CAP + gp] = make_uint2(u1, (unsigned)(i0 + 1)); }
            }
            if (u2 < tau) {
                int p = atomicAdd(&s_cnt[g], 1);
                if (p < CAPB) s_buf[g][p] = make_uint2(u2, (unsigned)(i0 + 2));
                else { int gp = atomicAdd(&counts[b * G_NUMS + g], 1);
                       if (gp < CAP) surv[(size_t)(b * G_NUMS + g) * CAP + gp] = make_uint2(u2, (unsigned)(i0 + 2)); }
            }
            if (u3 < tau) {
                int p = atomicAdd(&s_cnt[g], 1);
                if (p < CAPB) s_buf[g][p] = make_uint2(u3, (unsigned)(i0 + 3));
                else { int gp = atomicAdd(&counts[b * G_NUMS + g], 1);
                       if (gp < CAP) surv[(size_t)(b * G_NUMS + g) * CAP + gp] = make_uint2(u3, (unsigned)(i0 + 3)); }
            }
        }
    }
    __syncthreads();

    // flush: one wave per g (round-robin), single global atomic per (block,g)
    for (int g = wid; g < G_NUMS; g += NWAVES) {
        int n = s_cnt[g]; if (n > CAPB) n = CAPB;
        int base = 0;
        if (lane == 0 && n > 0) base = atomicAdd(&counts[b * G_NUMS + g], n);
        base = __shfl(base, 0);
        for (int i = lane; i < n; i += 64) {
            int p = base + i;
            if (p < CAP) surv[(size_t)(b * G_NUMS + g) * CAP + p] = s_buf[g][i];
        }
    }
}

// ---- 3x3 symmetric eigensolve (Jacobi, double) ----
__device__ void eig3(const float cf[6], double lam_out[3], double dir_out[3]) {
    double a[3][3], v[3][3];
    a[0][0] = cf[0]; a[0][1] = cf[1]; a[0][2] = cf[2];
    a[1][0] = cf[1]; a[1][1] = cf[3]; a[1][2] = cf[4];
    a[2][0] = cf[2]; a[2][1] = cf[4]; a[2][2] = cf[5];
    for (int i = 0; i < 3; i++)
        for (int j = 0; j < 3; j++) v[i][j] = (i == j) ? 1.0 : 0.0;

    for (int sweep = 0; sweep < 12; sweep++) {
        double off = a[0][1] * a[0][1] + a[0][2] * a[0][2] + a[1][2] * a[1][2];
        if (off == 0.0) break;
        for (int p = 0; p < 2; p++) {
            for (int q = p + 1; q < 3; q++) {
                double apq = a[p][q];
                if (apq == 0.0) continue;
                double app = a[p][p], aqq = a[q][q];
                double theta = (aqq - app) / (2.0 * apq);
                double t = (theta >= 0.0 ? 1.0 : -1.0) /
                           (fabs(theta) + sqrt(theta * theta + 1.0));
                double c = 1.0 / sqrt(t * t + 1.0);
                double s = t * c;
                a[p][p] = app - t * apq;
                a[q][q] = aqq + t * apq;
                a[p][q] = 0.0; a[q][p] = 0.0;
                for (int r = 0; r < 3; r++) {
                    if (r == p || r == q) continue;
                    double arp = a[r][p], arq = a[r][q];
                    a[r][p] = c * arp - s * arq; a[p][r] = a[r][p];
                    a[r][q] = s * arp + c * arq; a[q][r] = a[r][q];
                }
                for (int r = 0; r < 3; r++) {
                    double vrp = v[r][p], vrq = v[r][q];
                    v[r][p] = c * vrp - s * vrq;
                    v[r][q] = s * vrp + c * vrq;
                }
            }
        }
    }
    double l0 = a[0][0], l1 = a[1][1], l2 = a[2][2];
    int i0 = 0, i1 = 1, i2 = 2;
    if (l0 > l1) { double t = l0; l0 = l1; l1 = t; int ti = i0; i0 = i1; i1 = ti; }
    if (l1 > l2) { double t = l1; l1 = l2; l2 = t; int ti = i1; i1 = i2; i2 = ti; }
    if (l0 > l1) { double t = l0; l0 = l1; l1 = t; int ti = i0; i0 = i1; i1 = ti; }
    lam_out[0] = l0; lam_out[1] = l1; lam_out[2] = l2;
    dir_out[0] = v[0][i2]; dir_out[1] = v[1][i2]; dir_out[2] = v[2][i2];
}

__global__ __launch_bounds__(TPB, 2)
void mono_kernel(const float* __restrict__ pts, float* __restrict__ out,
                 float4* __restrict__ qtau0, float4* __restrict__ qtau1,
                 float* __restrict__ gmeans, float* __restrict__ covs,
                 int* __restrict__ counts, uint2* __restrict__ surv, int B) {
    cg::grid_group grid = cg::this_grid();

    __shared__ unsigned s_hist[BINS];
    __shared__ uint2 s_buf[G_NUMS][CAPB];
    __shared__ float4 s_qt[G_NUMS];
    __shared__ int s_cnt[G_NUMS];
    __shared__ unsigned s_wsum[NWAVES];
    __shared__ unsigned s_T;
    __shared__ int s_nd, s_nt;
    __shared__ int s_sel[G_SIZE];
    __shared__ unsigned s_tu[TIE_CAP];
    __shared__ int s_ti[TIE_CAP];
    __shared__ float s_acc[3], s_cov[6];
    __shared__ float s_dir[256][3];
    __shared__ float s_gm[256][3];
    __shared__ float s_pe[NWAVES], s_ps[NWAVES];

    const int tid = threadIdx.x, lane = tid & 63, wid = tid >> 6;
    const int blk = blockIdx.x;
    const int nblk = gridDim.x;
    const int NG = B * G_NUMS;

    // ================= phase A: tau0 per (b,g) =================
    if (blk < NG) {
        int b = blk % B, g = blk / B, gi = b * G_NUMS + g;
        const float* P = pts + (size_t)b * (N_PTS * 3);
        float qx = P[(size_t)g * PT_STRIDE * 3 + 0];
        float qy = P[(size_t)g * PT_STRIDE * 3 + 1];
        float qz = P[(size_t)g * PT_STRIDE * 3 + 2];
        unsigned tau = sample_tau((const float4*)P, qx, qy, qz,
                                  s_hist, s_wsum, &s_T, tid, lane, wid);
        if (tid == 0) {
            qtau0[gi] = make_float4(qx, qy, qz, __uint_as_float(tau));
            counts[gi] = 0;
        }
    }
    __threadfence(); grid.sync();

    // ================= phase B: filter 0 =================
    filter_phase(pts, qtau0, counts, surv, B, s_qt, s_cnt, s_buf,
                 tid, lane, wid, blk, nblk);
    __threadfence(); grid.sync();

    // ============ phases C/E: select (templated by hand) ============
#pragma unroll 1
    for (int phase = 0; phase < 2; ++phase) {
        if (blk < NG) {
            int b = blk % B, g = blk / B, gi = b * G_NUMS + g;
            const float* P = pts + (size_t)b * (N_PTS * 3);
            const float4* P4 = (const float4*)P;
            const float4 qt = (phase == 0) ? qtau0[gi] : qtau1[gi];
            const unsigned tau = __float_as_uint(qt.w);
            int S = counts[gi]; if (S > CAP) S = CAP;
            const uint2* sv = surv + (size_t)gi * CAP;

            for (int j = tid; j < BINS; j += TPB) s_hist[j] = 0u;
            if (tid == 0) { s_T = 0u; s_nd = 0; s_nt = 0; }
            if (tid < 3) s_acc[tid] = 0.f;
            if (tid < 6) s_cov[tid] = 0.f;
            __syncthreads();

            unsigned hb = 32u - (unsigned)__clz(tau - 1u);
            unsigned sh = hb > 12u ? hb - 12u : 0u;
            for (int i = tid; i < S; i += TPB) atomicAdd(&s_hist[sv[i].x >> sh], 1u);
            __syncthreads();
            unsigned T2 = find_bin(s_hist, s_wsum, &s_T, G_SIZE, tid, lane, wid);
            const unsigned lo = T2 << sh;

            for (int i = tid; i < S; i += TPB) {
                unsigned u = sv[i].x;
                if (u < lo) {
                    int p = atomicAdd(&s_nd, 1);
                    if (p < G_SIZE) s_sel[p] = (int)sv[i].y;
                } else if ((u >> sh) == T2) {
                    int p = atomicAdd(&s_nt, 1);
                    if (p < TIE_CAP) { s_tu[p] = u; s_ti[p] = (int)sv[i].y; }
                }
            }
            __syncthreads();
            if (tid == 0) {
                int nd = s_nd; if (nd > G_SIZE) nd = G_SIZE;
                int need = G_SIZE - nd;
                int ec = s_nt; if (ec > TIE_CAP) ec = TIE_CAP;
                for (int a = 0; a < need && a < ec; ++a) {
                    int best = a;
                    for (int j = a + 1; j < ec; ++j)
                        if (s_tu[j] < s_tu[best] ||
                            (s_tu[j] == s_tu[best] && s_ti[j] < s_ti[best])) best = j;
                    unsigned tu = s_tu[best]; s_tu[best] = s_tu[a]; s_tu[a] = tu;
                    int ti = s_ti[best]; s_ti[best] = s_ti[a]; s_ti[a] = ti;
                    s_sel[nd + a] = s_ti[a];
                }
            }
            __syncthreads();

            float px = 0.f, py = 0.f, pz = 0.f;
            if (tid < G_SIZE) {
                const float* pp = P + 3 * (size_t)s_sel[tid];
                px = pp[0]; py = pp[1]; pz = pp[2];
                atomicAdd(&s_acc[0], px);
                atomicAdd(&s_acc[1], py);
                atomicAdd(&s_acc[2], pz);
            }
            __syncthreads();
            const float mx = s_acc[0] * (1.0f / G_SIZE);
            const float my = s_acc[1] * (1.0f / G_SIZE);
            const float mz = s_acc[2] * (1.0f / G_SIZE);

            if (phase == 0) {
                if (tid < 3) gmeans[gi * 3 + tid] = (tid == 0 ? mx : tid == 1 ? my : mz);
                unsigned tau1 = sample_tau(P4, mx, my, mz,
                                           s_hist, s_wsum, &s_T, tid, lane, wid);
                if (tid == 0) {
                    qtau1[gi] = make_float4(mx, my, mz, __uint_as_float(tau1));
                    counts[gi] = 0;
                }
            } else {
                if (tid < G_SIZE) {
                    float x = px - mx, y = py - my, z = pz - mz;
                    atomicAdd(&s_cov[0], x * x);
                    atomicAdd(&s_cov[1], x * y);
                    atomicAdd(&s_cov[2], x * z);
                    atomicAdd(&s_cov[3], y * y);
                    atomicAdd(&s_cov[4], y * z);
                    atomicAdd(&s_cov[5], z * z);
                }
                __syncthreads();
                if (tid < 6) covs[gi * 6 + tid] = s_cov[tid] * (1.0f / G_SIZE);
            }
        }
        __threadfence(); grid.sync();

        // ================= phase D: filter 1 (between selects) =================
        if (phase == 0) {
            filter_phase(pts, qtau1, counts, surv, B, s_qt, s_cnt, s_buf,
                         tid, lane, wid, blk, nblk);
            __threadfence(); grid.sync();
        }
    }

    // ================= phase F: finalize (block 0) =================
    if (blk == 0) {
        float et = 0.f;
        if (tid < NG) {
            float cf[6];
#pragma unroll
            for (int j = 0; j < 6; j++) cf[j] = covs[tid * 6 + j];
            double lam[3], dir[3];
            eig3(cf, lam, dir);
            double denom = lam[0] + lam[1] + lam[2] + 1e-9;
            et = (float)((lam[2] - lam[1]) / denom);
            s_dir[tid][0] = (float)dir[0];
            s_dir[tid][1] = (float)dir[1];
            s_dir[tid][2] = (float)dir[2];
            s_gm[tid][0] = gmeans[tid * 3 + 0];
            s_gm[tid][1] = gmeans[tid * 3 + 1];
            s_gm[tid][2] = gmeans[tid * 3 + 2];
        }
        __syncthreads();

        float st = 0.f;
        if (tid < NG) {
            int b = tid / G_NUMS, g = tid % G_NUMS;
            float gx = s_gm[tid][0], gy = s_gm[tid][1], gz = s_gm[tid][2];
            float bd = 3.4e38f; int bj = 0;
            for (int gg = 0; gg < G_NUMS; gg++) {
                if (gg == g) continue;
                int o = b * G_NUMS + gg;
                float dx = gx - s_gm[o][0];
                float dy = gy - s_gm[o][1];
                float dz = gz - s_gm[o][2];
                float d = dx * dx + dy * dy + dz * dz;
                if (d < bd) { bd = d; bj = gg; }
            }
            int o = b * G_NUMS + bj;
            float cosv = s_dir[tid][0] * s_dir[o][0] +
                         s_dir[tid][1] * s_dir[o][1] +
                         s_dir[tid][2] * s_dir[o][2];
            st = 1.f - cosv * cosv;
        }

        float e = et, s2 = st;
#pragma unroll
        for (int off = 32; off > 0; off >>= 1) {
            e += __shfl_down(e, off);
            s2 += __shfl_down(s2, off);
        }
        if (lane == 0) { s_pe[wid] = e; s_ps[wid] = s2; }
        __syncthreads();
        if (tid == 0) {
            float se = 0.f, ss = 0.f;
            for (int w = 0; w < NWAVES; w++) { se += s_pe[w]; ss += s_ps[w]; }
            out[0] = -se / (float)B + ss / (float)NG;
        }
    }
}

extern "C" void kernel_launch(void* const* d_in, const int* in_sizes, int n_in,
                              void* d_out, int out_size, void* d_ws, size_t ws_size,
                              hipStream_t stream) {
    const float* pts = (const float*)d_in[0];
    float* out = (float*)d_out;
    int B = in_sizes[0] / (N_PTS * 3);   // 8
    const int NG = B * G_NUMS;           // 240

    float4* qtau0 = (float4*)d_ws;                 // NG
    float4* qtau1 = qtau0 + NG;                    // NG
    float* gmeans = (float*)(qtau1 + NG);          // NG*3
    float* covs = gmeans + NG * 3;                 // NG*6
    int* counts = (int*)(covs + NG * 6);           // NG (padded to 256)
    uint2* surv = (uint2*)(counts + 256);          // NG*CAP*8 B

    void* args[] = {(void*)&pts, (void*)&out, (void*)&qtau0, (void*)&qtau1,
                    (void*)&gmeans, (void*)&covs, (void*)&counts, (void*)&surv,
                    (void*)&B};
    hipLaunchCooperativeKernel((const void*)mono_kernel, dim3(NBLK), dim3(TPB),
                               args, 0, stream);
}